// Round 1
// baseline (664.404 us; speedup 1.0000x reference)
//
#include <hip/hip_runtime.h>
#include <math.h>

// MSDeformAttn, fp32, correctness-first structured version.
// N=2, C=256, M=8, L=4, P=4, D=32, LEN=21760
// Levels: (128,128),(64,64),(32,32),(16,16); starts 0,16384,20480,21504

constexpr int NB  = 2;
constexpr int C   = 256;
constexpr int M   = 8;
constexpr int LV  = 4;
constexpr int P   = 4;
constexpr int D   = 32;
constexpr int LEN = 21760;
constexpr int QB  = 16;     // rows (queries) per block

// ---------------------------------------------------------------------------
// Kernel 1: value = input_flatten @ W_val + b_val, stored as value[n][m][pix][d]
// rows = NB*LEN = 43520, block handles QB rows x 256 cols
// ---------------------------------------------------------------------------
__global__ __launch_bounds__(256) void k_valproj(
    const float* __restrict__ inflat, const float* __restrict__ Wv,
    const float* __restrict__ bv, float* __restrict__ value) {
  __shared__ float rows[QB][C];
  const int t  = threadIdx.x;
  const int r0 = blockIdx.x * QB;

  for (int rr = 0; rr < QB; ++rr)
    rows[rr][t] = inflat[(size_t)(r0 + rr) * C + t];
  __syncthreads();

  float acc[QB];
#pragma unroll
  for (int rr = 0; rr < QB; ++rr) acc[rr] = 0.f;

#pragma unroll 4
  for (int k = 0; k < C; ++k) {
    const float w = Wv[k * C + t];
#pragma unroll
    for (int rr = 0; rr < QB; ++rr) acc[rr] += rows[rr][k] * w;
  }

  const float bb = bv[t];
  const int m = t >> 5, d = t & 31;
  for (int rr = 0; rr < QB; ++rr) {
    const int r = r0 + rr;
    const int n = r / LEN, i = r % LEN;
    value[(((size_t)(n * M + m)) * LEN + i) * D + d] = acc[rr] + bb;
  }
}

// ---------------------------------------------------------------------------
// Kernel 2: fused sampling-offset GEMM + attn GEMM + softmax + bilinear sample
// one block = QB queries of one batch; 256 threads
// ---------------------------------------------------------------------------
__global__ __launch_bounds__(256) void k_sample(
    const float* __restrict__ query, const float* __restrict__ refp,
    const float* __restrict__ Woff, const float* __restrict__ boff,
    const float* __restrict__ Wattn, const float* __restrict__ battn,
    const float* __restrict__ value, float* __restrict__ accout) {
  __shared__ float qrows[QB][C];        // 16 KiB
  __shared__ float offs[QB][C];         // 16 KiB (M*L*P*2 = 256)
  __shared__ float attw[QB][M * LV * P];// 8 KiB  (128)
  __shared__ float refs[QB][LV][2];     // 512 B

  const int t  = threadIdx.x;
  const int b  = blockIdx.x;
  const int n  = b / (LEN / QB);
  const int q0 = (b % (LEN / QB)) * QB;

  for (int rr = 0; rr < QB; ++rr)
    qrows[rr][t] = query[((size_t)n * LEN + q0 + rr) * C + t];
  if (t < QB * LV * 2) {
    const int rr = t / (LV * 2);
    const int rem = t % (LV * 2);
    refs[rr][rem >> 1][rem & 1] =
        refp[((size_t)n * LEN + q0 + rr) * (LV * 2) + rem];
  }
  __syncthreads();

  // ---- sampling offsets: 256 columns ----
  {
    float acc[QB];
#pragma unroll
    for (int rr = 0; rr < QB; ++rr) acc[rr] = 0.f;
#pragma unroll 4
    for (int k = 0; k < C; ++k) {
      const float w = Woff[k * 256 + t];
#pragma unroll
      for (int rr = 0; rr < QB; ++rr) acc[rr] += qrows[rr][k] * w;
    }
    const float bb = boff[t];
    for (int rr = 0; rr < QB; ++rr) offs[rr][t] = acc[rr] + bb;
  }

  // ---- attention logits: 128 columns ----
  if (t < 128) {
    float acc[QB];
#pragma unroll
    for (int rr = 0; rr < QB; ++rr) acc[rr] = 0.f;
#pragma unroll 4
    for (int k = 0; k < C; ++k) {
      const float w = Wattn[k * 128 + t];
#pragma unroll
      for (int rr = 0; rr < QB; ++rr) acc[rr] += qrows[rr][k] * w;
    }
    const float bb = battn[t];
    for (int rr = 0; rr < QB; ++rr) attw[rr][t] = acc[rr] + bb;
  }
  __syncthreads();

  // ---- softmax over L*P = 16 per (q, m); 128 tasks ----
  if (t < QB * M) {
    const int rr = t >> 3, m = t & 7;
    float v[16], mx = -1e30f;
#pragma unroll
    for (int j = 0; j < 16; ++j) { v[j] = attw[rr][m * 16 + j]; mx = fmaxf(mx, v[j]); }
    float s = 0.f;
#pragma unroll
    for (int j = 0; j < 16; ++j) { v[j] = __expf(v[j] - mx); s += v[j]; }
    const float inv = 1.f / s;
#pragma unroll
    for (int j = 0; j < 16; ++j) attw[rr][m * 16 + j] = v[j] * inv;
  }
  __syncthreads();

  // ---- bilinear sampling + weighted accumulate ----
  const int Hs[4] = {128, 64, 32, 16};
  const int Ws[4] = {128, 64, 32, 16};
  const int st[4] = {0, 16384, 20480, 21504};
  const int m = t >> 5, d = t & 31;

  for (int rr = 0; rr < QB; ++rr) {
    float acc = 0.f;
#pragma unroll
    for (int l = 0; l < LV; ++l) {
      const int H = Hs[l], W = Ws[l];
      const float* vbase =
          value + (((size_t)(n * M + m)) * LEN + st[l]) * D + d;
      const float rx = refs[rr][l][0], ry = refs[rr][l][1];
#pragma unroll
      for (int p = 0; p < P; ++p) {
        const int j = (m * LV + l) * P + p;
        const float ox = offs[rr][2 * j], oy = offs[rr][2 * j + 1];
        const float aw = attw[rr][j];
        const float x = rx * (float)W + ox - 0.5f;
        const float y = ry * (float)H + oy - 0.5f;
        const float x0f = floorf(x), y0f = floorf(y);
        const float fx = x - x0f, fy = y - y0f;
        const int x0 = (int)x0f, y0 = (int)y0f;
        const int x1 = x0 + 1, y1 = y0 + 1;
        const bool vx0 = (x0 >= 0) & (x0 < W), vx1 = (x1 >= 0) & (x1 < W);
        const bool vy0 = (y0 >= 0) & (y0 < H), vy1 = (y1 >= 0) & (y1 < H);
        const float v00 = (vx0 && vy0) ? vbase[(size_t)(y0 * W + x0) * D] : 0.f;
        const float v01 = (vx1 && vy0) ? vbase[(size_t)(y0 * W + x1) * D] : 0.f;
        const float v10 = (vx0 && vy1) ? vbase[(size_t)(y1 * W + x0) * D] : 0.f;
        const float v11 = (vx1 && vy1) ? vbase[(size_t)(y1 * W + x1) * D] : 0.f;
        const float s = (1.f - fx) * (1.f - fy) * v00 + fx * (1.f - fy) * v01 +
                        (1.f - fx) * fy * v10 + fx * fy * v11;
        acc += aw * s;
      }
    }
    accout[((size_t)n * LEN + q0 + rr) * C + t] = acc;
  }
}

// ---------------------------------------------------------------------------
// Kernel 3: out = acc @ W_out + b_out
// ---------------------------------------------------------------------------
__global__ __launch_bounds__(256) void k_outproj(
    const float* __restrict__ accin, const float* __restrict__ Wo,
    const float* __restrict__ bo, float* __restrict__ out) {
  __shared__ float rows[QB][C];
  const int t  = threadIdx.x;
  const int r0 = blockIdx.x * QB;

  for (int rr = 0; rr < QB; ++rr)
    rows[rr][t] = accin[(size_t)(r0 + rr) * C + t];
  __syncthreads();

  float acc[QB];
#pragma unroll
  for (int rr = 0; rr < QB; ++rr) acc[rr] = 0.f;

#pragma unroll 4
  for (int k = 0; k < C; ++k) {
    const float w = Wo[k * C + t];
#pragma unroll
    for (int rr = 0; rr < QB; ++rr) acc[rr] += rows[rr][k] * w;
  }

  const float bb = bo[t];
  for (int rr = 0; rr < QB; ++rr)
    out[(size_t)(r0 + rr) * C + t] = acc[rr] + bb;
}

// ---------------------------------------------------------------------------
extern "C" void kernel_launch(void* const* d_in, const int* in_sizes, int n_in,
                              void* d_out, int out_size, void* d_ws, size_t ws_size,
                              hipStream_t stream) {
  const float* query = (const float*)d_in[0];
  const float* refp  = (const float*)d_in[1];
  const float* infl  = (const float*)d_in[2];
  const float* Woff  = (const float*)d_in[3];
  const float* boff  = (const float*)d_in[4];
  const float* Wattn = (const float*)d_in[5];
  const float* battn = (const float*)d_in[6];
  const float* Wval  = (const float*)d_in[7];
  const float* bval  = (const float*)d_in[8];
  const float* Wout  = (const float*)d_in[9];
  const float* bout  = (const float*)d_in[10];
  float* out = (float*)d_out;

  float* value  = (float*)d_ws;                       // NB*M*LEN*D floats
  float* accbuf = value + (size_t)NB * M * LEN * D;   // NB*LEN*C floats

  const int nrow_blocks = (NB * LEN) / QB;            // 2720

  k_valproj<<<nrow_blocks, 256, 0, stream>>>(infl, Wval, bval, value);
  k_sample<<<NB * (LEN / QB), 256, 0, stream>>>(query, refp, Woff, boff,
                                                Wattn, battn, value, accbuf);
  k_outproj<<<nrow_blocks, 256, 0, stream>>>(accbuf, Wout, bout, out);
}

// Round 2
// 527.007 us; speedup vs baseline: 1.2607x; 1.2607x over previous
//
#include <hip/hip_runtime.h>
#include <math.h>

// MSDeformAttn fp32. N=2, C=256, M=8, L=4, P=4, D=32, LEN=21760
// R2: descriptor-dedup sampling + 4x4 register-tiled GEMMs.

constexpr int NB  = 2;
constexpr int C   = 256;
constexpr int M   = 8;
constexpr int LV  = 4;
constexpr int P   = 4;
constexpr int D   = 32;
constexpr int LEN = 21760;
constexpr int QB  = 16;

// ---------------------------------------------------------------------------
// Kernel 1: value = input_flatten @ W_val + b_val -> value[n][m][pix][d]
// ---------------------------------------------------------------------------
__global__ __launch_bounds__(256) void k_valproj(
    const float* __restrict__ inflat, const float* __restrict__ Wv,
    const float* __restrict__ bv, float* __restrict__ value) {
  __shared__ __align__(16) float rows[QB][C];
  const int t  = threadIdx.x;
  const int r0 = blockIdx.x * QB;

  for (int rr = 0; rr < QB; ++rr)
    rows[rr][t] = inflat[(size_t)(r0 + rr) * C + t];
  __syncthreads();

  const int c4    = (t & 63) * 4;
  const int rbase = (t >> 6) * 4;
  float acc[4][4];
#pragma unroll
  for (int r = 0; r < 4; ++r)
#pragma unroll
    for (int c = 0; c < 4; ++c) acc[r][c] = 0.f;

  for (int k = 0; k < C; k += 4) {
    float4 q[4];
#pragma unroll
    for (int r = 0; r < 4; ++r) q[r] = *(const float4*)&rows[rbase + r][k];
#pragma unroll
    for (int kk = 0; kk < 4; ++kk) {
      const float4 w = *(const float4*)&Wv[(size_t)(k + kk) * C + c4];
#pragma unroll
      for (int r = 0; r < 4; ++r) {
        const float qv = ((const float*)&q[r])[kk];
        acc[r][0] += qv * w.x; acc[r][1] += qv * w.y;
        acc[r][2] += qv * w.z; acc[r][3] += qv * w.w;
      }
    }
  }
  const float4 bb = *(const float4*)&bv[c4];
  const int m = c4 >> 5, dd = c4 & 31;
#pragma unroll
  for (int r = 0; r < 4; ++r) {
    const int row = r0 + rbase + r;
    const int n = row / LEN, i = row % LEN;
    float4 o;
    o.x = acc[r][0] + bb.x; o.y = acc[r][1] + bb.y;
    o.z = acc[r][2] + bb.z; o.w = acc[r][3] + bb.w;
    *(float4*)&value[(((size_t)(n * M + m)) * LEN + i) * D + dd] = o;
  }
}

// ---------------------------------------------------------------------------
// Kernel 2: fused offsets/attn GEMM + softmax + descriptor + bilinear sample
// ---------------------------------------------------------------------------
__global__ __launch_bounds__(256) void k_sample(
    const float* __restrict__ query, const float* __restrict__ refp,
    const float* __restrict__ Woff, const float* __restrict__ boff,
    const float* __restrict__ Wattn, const float* __restrict__ battn,
    const float* __restrict__ value, float* __restrict__ accout) {
  __shared__ __align__(16) float smemA[QB * C];   // 16 KiB: qrows, later descriptors
  __shared__ __align__(16) float offs[QB][256];   // 16 KiB
  __shared__ __align__(16) float attw[QB][128];   // 8 KiB
  __shared__ float refs[QB][8];                   // 512 B

  const int t  = threadIdx.x;
  const int b  = blockIdx.x;
  const int n  = b / (LEN / QB);
  const int q0 = (b % (LEN / QB)) * QB;

  for (int rr = 0; rr < QB; ++rr)
    smemA[rr * C + t] = query[((size_t)n * LEN + q0 + rr) * C + t];
  if (t < QB * 8)
    refs[t >> 3][t & 7] = refp[((size_t)n * LEN + q0) * 8 + t];
  __syncthreads();

  // ---- fused GEMM: 4 offset cols + 2 attn cols per thread, 4 rows ----
  {
    const int c4    = (t & 63) * 4;
    const int c2    = (t & 63) * 2;
    const int rbase = (t >> 6) * 4;
    float ao[4][4], aa[4][2];
#pragma unroll
    for (int r = 0; r < 4; ++r) {
#pragma unroll
      for (int c = 0; c < 4; ++c) ao[r][c] = 0.f;
      aa[r][0] = 0.f; aa[r][1] = 0.f;
    }
    for (int k = 0; k < C; k += 4) {
      float4 q[4];
#pragma unroll
      for (int r = 0; r < 4; ++r) q[r] = *(const float4*)&smemA[(rbase + r) * C + k];
#pragma unroll
      for (int kk = 0; kk < 4; ++kk) {
        const float4 w  = *(const float4*)&Woff[(size_t)(k + kk) * 256 + c4];
        const float2 wa = *(const float2*)&Wattn[(size_t)(k + kk) * 128 + c2];
#pragma unroll
        for (int r = 0; r < 4; ++r) {
          const float qv = ((const float*)&q[r])[kk];
          ao[r][0] += qv * w.x; ao[r][1] += qv * w.y;
          ao[r][2] += qv * w.z; ao[r][3] += qv * w.w;
          aa[r][0] += qv * wa.x; aa[r][1] += qv * wa.y;
        }
      }
    }
    const float4 bo4 = *(const float4*)&boff[c4];
    const float2 ba2 = *(const float2*)&battn[c2];
#pragma unroll
    for (int r = 0; r < 4; ++r) {
      float4 o;
      o.x = ao[r][0] + bo4.x; o.y = ao[r][1] + bo4.y;
      o.z = ao[r][2] + bo4.z; o.w = ao[r][3] + bo4.w;
      *(float4*)&offs[rbase + r][c4] = o;
      attw[rbase + r][c2]     = aa[r][0] + ba2.x;
      attw[rbase + r][c2 + 1] = aa[r][1] + ba2.y;
    }
  }
  __syncthreads();

  // ---- softmax over 16 per (q, m) ----
  if (t < QB * M) {
    const int rr = t >> 3, m = t & 7;
    float v[16], mx = -1e30f;
#pragma unroll
    for (int j = 0; j < 16; ++j) { v[j] = attw[rr][m * 16 + j]; mx = fmaxf(mx, v[j]); }
    float s = 0.f;
#pragma unroll
    for (int j = 0; j < 16; ++j) { v[j] = __expf(v[j] - mx); s += v[j]; }
    const float inv = 1.f / s;
#pragma unroll
    for (int j = 0; j < 16; ++j) attw[rr][m * 16 + j] = v[j] * inv;
  }
  __syncthreads();

  // ---- sampling: 4 iterations of (descriptor phase A, gather phase B) ----
  int4*   didx = (int4*)smemA;              // [512]
  float4* dwt  = (float4*)(smemA + 2048);   // [512]
  const int slot = t >> 6;
  const int mB   = (t >> 3) & 7;
  const int d4   = t & 7;
  const uint32_t baseoff =
      ((uint32_t)((n * M + mB) * LEN) * D + (uint32_t)d4 * 4) * 4u;  // bytes
  const char* vbase = (const char*)value;

  for (int it = 0; it < 4; ++it) {
    // phase A: 512 descriptors (4 rr-slots x 128 j), 2 per thread
#pragma unroll
    for (int e2 = 0; e2 < 2; ++e2) {
      const int e  = t + e2 * 256;
      const int sl = e >> 7, qq = e & 127;      // qq = j*8 + m
      const int m = qq & 7, j = qq >> 3, l = j >> 2;
      const int rr = it * 4 + sl;
      const int jo = m * 16 + j;
      const float ox = offs[rr][2 * jo], oy = offs[rr][2 * jo + 1];
      const float aw = attw[rr][jo];
      const float rx = refs[rr][l * 2 + 0], ry = refs[rr][l * 2 + 1];
      const int W = 128 >> l;                    // square levels
      const int st_l = ((16384 - (16384 >> (2 * l))) * 4) / 3;  // 0,16384,20480,21504
      const float x = rx * (float)W + ox - 0.5f;
      const float y = ry * (float)W + oy - 0.5f;
      const float x0f = floorf(x), y0f = floorf(y);
      const float fx = x - x0f, fy = y - y0f;
      const int x0 = (int)x0f, y0 = (int)y0f;
      const int x1 = x0 + 1, y1 = y0 + 1;
      const int x0c = min(max(x0, 0), W - 1), x1c = min(max(x1, 0), W - 1);
      const int y0c = min(max(y0, 0), W - 1), y1c = min(max(y1, 0), W - 1);
      float wx0 = 1.f - fx, wx1 = fx, wy0 = 1.f - fy, wy1 = fy;
      if (x0 < 0 || x0 >= W) wx0 = 0.f;
      if (x1 < 0 || x1 >= W) wx1 = 0.f;
      if (y0 < 0 || y0 >= W) wy0 = 0.f;
      if (y1 < 0 || y1 >= W) wy1 = 0.f;
      int4 idx;
      idx.x = st_l + y0c * W + x0c;
      idx.y = st_l + y0c * W + x1c;
      idx.z = st_l + y1c * W + x0c;
      idx.w = st_l + y1c * W + x1c;
      float4 w4;
      w4.x = wx0 * wy0 * aw; w4.y = wx1 * wy0 * aw;
      w4.z = wx0 * wy1 * aw; w4.w = wx1 * wy1 * aw;
      didx[e] = idx;
      dwt[e]  = w4;
    }
    __syncthreads();

    // phase B: gather + FMA; thread = (slot, m, d4), 4 d-channels each
    {
      const int rr = it * 4 + slot;
      float4 acc = {0.f, 0.f, 0.f, 0.f};
#pragma unroll
      for (int j = 0; j < 16; ++j) {
        const int e = slot * 128 + j * 8 + mB;
        const int4   idx = didx[e];
        const float4 w   = dwt[e];
        const float4 v00 = *(const float4*)(vbase + baseoff + ((uint32_t)idx.x << 7));
        const float4 v01 = *(const float4*)(vbase + baseoff + ((uint32_t)idx.y << 7));
        const float4 v10 = *(const float4*)(vbase + baseoff + ((uint32_t)idx.z << 7));
        const float4 v11 = *(const float4*)(vbase + baseoff + ((uint32_t)idx.w << 7));
        acc.x += w.x * v00.x; acc.y += w.x * v00.y; acc.z += w.x * v00.z; acc.w += w.x * v00.w;
        acc.x += w.y * v01.x; acc.y += w.y * v01.y; acc.z += w.y * v01.z; acc.w += w.y * v01.w;
        acc.x += w.z * v10.x; acc.y += w.z * v10.y; acc.z += w.z * v10.z; acc.w += w.z * v10.w;
        acc.x += w.w * v11.x; acc.y += w.w * v11.y; acc.z += w.w * v11.z; acc.w += w.w * v11.w;
      }
      *(float4*)&accout[((size_t)n * LEN + q0 + rr) * C + mB * 32 + d4 * 4] = acc;
    }
    __syncthreads();
  }
}

// ---------------------------------------------------------------------------
// Kernel 3: out = acc @ W_out + b_out
// ---------------------------------------------------------------------------
__global__ __launch_bounds__(256) void k_outproj(
    const float* __restrict__ accin, const float* __restrict__ Wo,
    const float* __restrict__ bo, float* __restrict__ out) {
  __shared__ __align__(16) float rows[QB][C];
  const int t  = threadIdx.x;
  const int r0 = blockIdx.x * QB;

  for (int rr = 0; rr < QB; ++rr)
    rows[rr][t] = accin[(size_t)(r0 + rr) * C + t];
  __syncthreads();

  const int c4    = (t & 63) * 4;
  const int rbase = (t >> 6) * 4;
  float acc[4][4];
#pragma unroll
  for (int r = 0; r < 4; ++r)
#pragma unroll
    for (int c = 0; c < 4; ++c) acc[r][c] = 0.f;

  for (int k = 0; k < C; k += 4) {
    float4 q[4];
#pragma unroll
    for (int r = 0; r < 4; ++r) q[r] = *(const float4*)&rows[rbase + r][k];
#pragma unroll
    for (int kk = 0; kk < 4; ++kk) {
      const float4 w = *(const float4*)&Wo[(size_t)(k + kk) * C + c4];
#pragma unroll
      for (int r = 0; r < 4; ++r) {
        const float qv = ((const float*)&q[r])[kk];
        acc[r][0] += qv * w.x; acc[r][1] += qv * w.y;
        acc[r][2] += qv * w.z; acc[r][3] += qv * w.w;
      }
    }
  }
  const float4 bb = *(const float4*)&bo[c4];
#pragma unroll
  for (int r = 0; r < 4; ++r) {
    const size_t row = (size_t)(r0 + rbase + r);
    float4 o;
    o.x = acc[r][0] + bb.x; o.y = acc[r][1] + bb.y;
    o.z = acc[r][2] + bb.z; o.w = acc[r][3] + bb.w;
    *(float4*)&out[row * C + c4] = o;
  }
}

// ---------------------------------------------------------------------------
extern "C" void kernel_launch(void* const* d_in, const int* in_sizes, int n_in,
                              void* d_out, int out_size, void* d_ws, size_t ws_size,
                              hipStream_t stream) {
  const float* query = (const float*)d_in[0];
  const float* refp  = (const float*)d_in[1];
  const float* infl  = (const float*)d_in[2];
  const float* Woff  = (const float*)d_in[3];
  const float* boff  = (const float*)d_in[4];
  const float* Wattn = (const float*)d_in[5];
  const float* battn = (const float*)d_in[6];
  const float* Wval  = (const float*)d_in[7];
  const float* bval  = (const float*)d_in[8];
  const float* Wout  = (const float*)d_in[9];
  const float* bout  = (const float*)d_in[10];
  float* out = (float*)d_out;

  float* value  = (float*)d_ws;                       // NB*M*LEN*D floats
  float* accbuf = value + (size_t)NB * M * LEN * D;   // NB*LEN*C floats

  const int nrow_blocks = (NB * LEN) / QB;            // 2720

  k_valproj<<<nrow_blocks, 256, 0, stream>>>(infl, Wval, bval, value);
  k_sample<<<NB * (LEN / QB), 256, 0, stream>>>(query, refp, Woff, boff,
                                                Wattn, battn, value, accbuf);
  k_outproj<<<nrow_blocks, 256, 0, stream>>>(accbuf, Wout, bout, out);
}